// Round 1
// baseline (348.199 us; speedup 1.0000x reference)
//
#include <hip/hip_runtime.h>

typedef unsigned short u16;
typedef unsigned int u32;
typedef __attribute__((ext_vector_type(8))) short short8;
typedef __attribute__((ext_vector_type(4))) float f32x4;
typedef __attribute__((ext_vector_type(4))) u32 u32x4;

#define DI __device__ __forceinline__

constexpr int NB = 8;
constexpr int NC = 768;
constexpr int NT = 1024;
constexpr int NH = 12;
constexpr int ND = 64;
constexpr int NBH = NB * NH;  // 96

DI u16 f2bf(float f) {
  u32 u = __builtin_bit_cast(u32, f);
  u += 0x7fffu + ((u >> 16) & 1u);
  return (u16)(u >> 16);
}
DI float bf2f(u16 h) {
  u32 u = (u32)h << 16;
  return __builtin_bit_cast(float, u);
}

DI void gld16(const void* g, void* l) {
  __builtin_amdgcn_global_load_lds((const __attribute__((address_space(1))) void*)g,
                                   (__attribute__((address_space(3))) void*)l, 16, 0, 0);
}

DI f32x4 mfma16(short8 a, short8 b, f32x4 c) {
  return __builtin_amdgcn_mfma_f32_16x16x32_bf16(a, b, c, 0, 0, 0);
}

// All bf16 tensors are stored in 128-byte "rows"; within each 128B chunk the
// byte offset is XOR-swizzled by ((row & 7) << 4) so that swizzled
// ds_read_b128 fragment reads are bank-conflict-free while global_load_lds
// stays a pure linear copy (swizzle baked into global storage, G21 pattern).

// ---- split+transpose: src [B][C][T] f32 -> dst [B][T][C] bf16 hi/lo (swizzled) ----
__global__ __launch_bounds__(256) void k_split_T(const float* __restrict__ src,
                                                 u16* __restrict__ dhi, u16* __restrict__ dlo) {
  __shared__ float tl[64][65];
  const int tid = threadIdx.x;
  const int t0 = blockIdx.x * 64, c0 = blockIdx.y * 64, b = blockIdx.z;
  const float* sp = src + ((size_t)b * NC + c0) * NT + t0;
  const int cr = tid >> 4, t4 = (tid & 15) * 4;
#pragma unroll
  for (int p = 0; p < 4; ++p) {
    const float4* s4 = (const float4*)(sp + (size_t)(cr + p * 16) * NT + t4);
    float4 v = *s4;
    tl[cr + p * 16][t4 + 0] = v.x;
    tl[cr + p * 16][t4 + 1] = v.y;
    tl[cr + p * 16][t4 + 2] = v.z;
    tl[cr + p * 16][t4 + 3] = v.w;
  }
  __syncthreads();
#pragma unroll
  for (int hh = 0; hh < 2; ++hh) {
    int gid = tid * 2 + hh;
    int t = gid >> 3, g = gid & 7;
    u16 hi[8], lo[8];
#pragma unroll
    for (int i = 0; i < 8; ++i) {
      float v = tl[g * 8 + i][t];
      u16 h = f2bf(v);
      hi[i] = h;
      lo[i] = f2bf(v - bf2f(h));
    }
    size_t base = ((size_t)(b * NT + t0 + t) * NC + c0) * 2;
    int off = (g * 16) ^ ((t & 7) << 4);
    *(u32x4*)((char*)dhi + base + off) = *(const u32x4*)hi;
    *(u32x4*)((char*)dlo + base + off) = *(const u32x4*)lo;
  }
}

// ---- split weights: w [O][C] f32 -> hi/lo bf16 [O][C] (swizzled by o&7) ----
__global__ __launch_bounds__(256) void k_split_W(const float* __restrict__ w,
                                                 u16* __restrict__ dhi, u16* __restrict__ dlo) {
  const int tid = threadIdx.x;
  const int c0 = blockIdx.x * 64, o0 = blockIdx.y * 64;
#pragma unroll
  for (int hh = 0; hh < 2; ++hh) {
    int gid = tid * 2 + hh;
    int o = gid >> 3, g = gid & 7;
    const float* s = w + (size_t)(o0 + o) * NC + c0 + g * 8;
    u16 hi[8], lo[8];
#pragma unroll
    for (int i = 0; i < 8; ++i) {
      float v = s[i];
      u16 h = f2bf(v);
      hi[i] = h;
      lo[i] = f2bf(v - bf2f(h));
    }
    size_t base = ((size_t)(o0 + o) * NC + c0) * 2;
    int off = (g * 16) ^ ((o & 7) << 4);
    *(u32x4*)((char*)dhi + base + off) = *(const u32x4*)hi;
    *(u32x4*)((char*)dlo + base + off) = *(const u32x4*)lo;
  }
}

// ---- projection GEMM, bf16x3 split, 128x128 tile, BK=64 ----
// EPI: 0=Q (bias, *0.125, out [bh][t][d] bf16 swz)   1=K (same, no scale)
//      2=V (bias, out [bh][d][t] bf16 swz)           3=Y (bias, out f32 [b][o][t])
template <int EPI>
__global__ __launch_bounds__(256) void k_proj(const u16* __restrict__ xhi, const u16* __restrict__ xlo,
                                              const u16* __restrict__ whi, const u16* __restrict__ wlo,
                                              const float* __restrict__ bias, void* __restrict__ outp) {
  constexpr int ORIENT = (EPI <= 1) ? 0 : 1;  // 0: C[t][o], 1: C[o][t]
  __shared__ u16 lds[4][128][64];  // xh, xl, wh, wl  (64 KiB)
  const int tid = threadIdx.x, lane = tid & 63, wid = tid >> 6;
  const int l15 = lane & 15, l4 = lane >> 4;
  const int wm = wid >> 1, wn = wid & 1;
  const int t0 = blockIdx.x * 128, o0 = blockIdx.y * 128, b = blockIdx.z;
  const u16* xh = xhi + (size_t)b * NT * NC;
  const u16* xl = xlo + (size_t)b * NT * NC;
  f32x4 acc[4][4] = {};
  const int srow = wid * 32 + (lane >> 3);
  const int scol8 = (lane & 7) * 8;
  for (int k0 = 0; k0 < NC; k0 += 64) {
    __syncthreads();
#pragma unroll
    for (int cc = 0; cc < 4; ++cc) {
      int r = srow + cc * 8;
      int lr = wid * 32 + cc * 8;
      gld16(xh + (size_t)(t0 + r) * NC + k0 + scol8, &lds[0][lr][0]);
      gld16(xl + (size_t)(t0 + r) * NC + k0 + scol8, &lds[1][lr][0]);
      gld16(whi + (size_t)(o0 + r) * NC + k0 + scol8, &lds[2][lr][0]);
      gld16(wlo + (size_t)(o0 + r) * NC + k0 + scol8, &lds[3][lr][0]);
    }
    __syncthreads();
#pragma unroll
    for (int ks = 0; ks < 2; ++ks) {
      const int kb2 = 2 * (ks * 32 + l4 * 8);
      const int xo = kb2 ^ ((l15 & 7) << 4);
      short8 xa_h[4], xa_l[4], wb_h[4], wb_l[4];
#pragma unroll
      for (int f = 0; f < 4; ++f) {
        int xr = ((ORIENT == 0) ? wm : wn) * 64 + f * 16 + l15;
        int wr = ((ORIENT == 0) ? wn : wm) * 64 + f * 16 + l15;
        xa_h[f] = *(const short8*)((const char*)&lds[0][xr][0] + xo);
        xa_l[f] = *(const short8*)((const char*)&lds[1][xr][0] + xo);
        wb_h[f] = *(const short8*)((const char*)&lds[2][wr][0] + xo);
        wb_l[f] = *(const short8*)((const char*)&lds[3][wr][0] + xo);
      }
#pragma unroll
      for (int m = 0; m < 4; ++m)
#pragma unroll
        for (int n = 0; n < 4; ++n) {
          if (ORIENT == 0) {
            acc[m][n] = mfma16(xa_h[m], wb_h[n], acc[m][n]);
            acc[m][n] = mfma16(xa_h[m], wb_l[n], acc[m][n]);
            acc[m][n] = mfma16(xa_l[m], wb_h[n], acc[m][n]);
          } else {
            acc[m][n] = mfma16(wb_h[m], xa_h[n], acc[m][n]);
            acc[m][n] = mfma16(wb_h[m], xa_l[n], acc[m][n]);
            acc[m][n] = mfma16(wb_l[m], xa_h[n], acc[m][n]);
          }
        }
    }
  }
  if (EPI <= 1) {
    u16* ob = (u16*)outp;
#pragma unroll
    for (int n = 0; n < 4; ++n) {
      int o = o0 + wn * 64 + n * 16 + l15;
      int h = o >> 6, d = o & 63;
      float bv = bias[o];
#pragma unroll
      for (int m = 0; m < 4; ++m)
#pragma unroll
        for (int j = 0; j < 4; ++j) {
          int t = t0 + wm * 64 + m * 16 + l4 * 4 + j;
          float v = acc[m][n][j] + bv;
          if (EPI == 0) v *= 0.125f;  // 1/sqrt(64) folded into q
          size_t rowb = ((size_t)(b * NH + h) * NT + t) * 128;
          *(u16*)((char*)ob + rowb + ((2 * d) ^ ((t & 7) << 4))) = f2bf(v);
        }
    }
  } else if (EPI == 2) {
    u16* ob = (u16*)outp;
#pragma unroll
    for (int m = 0; m < 4; ++m)
#pragma unroll
      for (int j = 0; j < 4; ++j) {
        int o = o0 + wm * 64 + m * 16 + l4 * 4 + j;
        int h = o >> 6, d = o & 63;
        float bv = bias[o];
#pragma unroll
        for (int n = 0; n < 4; ++n) {
          int t = t0 + wn * 64 + n * 16 + l15;
          float v = acc[m][n][j] + bv;
          size_t cb = (((size_t)(b * NH + h) * ND + d) * NT + (size_t)(t & ~63)) * 2;
          *(u16*)((char*)ob + cb + ((2 * (t & 63)) ^ ((d & 7) << 4))) = f2bf(v);
        }
      }
  } else {
    float* of = (float*)outp;
#pragma unroll
    for (int m = 0; m < 4; ++m)
#pragma unroll
      for (int j = 0; j < 4; ++j) {
        int o = o0 + wm * 64 + m * 16 + l4 * 4 + j;
        float bv = bias[o];
#pragma unroll
        for (int n = 0; n < 4; ++n) {
          int t = t0 + wn * 64 + n * 16 + l15;
          of[((size_t)b * NC + o) * NT + t] = acc[m][n][j] + bv;
        }
      }
  }
}

// ---- rk[t][j] = qs[t] . emb_rel_k[j], j=0..8 (band logits) ----
__global__ __launch_bounds__(256) void k_rk(const u16* __restrict__ qbf, const float* __restrict__ erk,
                                            float* __restrict__ rk) {
  const int idx = blockIdx.x * 256 + threadIdx.x;  // bh*1024 + t
  const int t = idx & (NT - 1);
  float qv[64];
  const u32x4* rowv = (const u32x4*)(qbf + (size_t)idx * 64);
#pragma unroll
  for (int g = 0; g < 8; ++g) {
    u32x4 v = rowv[g];
    const u16* pp = (const u16*)&v;
#pragma unroll
    for (int i = 0; i < 8; ++i) qv[g * 8 + i] = bf2f(pp[i]);  // storage order
  }
  const int xr = (t & 7) << 3;  // element-level swizzle of the stored row
#pragma unroll
  for (int j = 0; j < 9; ++j) {
    float s = 0.f;
#pragma unroll
    for (int p = 0; p < 64; ++p) s += qv[p] * erk[j * 64 + (p ^ xr)];
    rk[(size_t)idx * 9 + j] = s;
  }
}

// ---- fused attention: scores + band rel-k, unnormalized softmax, PV + band rel-v ----
__global__ __launch_bounds__(256) void k_attn(const u16* __restrict__ qbf, const u16* __restrict__ kbf,
                                              const u16* __restrict__ vbf, const float* __restrict__ rkw,
                                              const float* __restrict__ erv,
                                              u16* __restrict__ ohi, u16* __restrict__ olo) {
  __shared__ u16 q_lds[64][64];
  __shared__ u16 k_lds[64][64];
  __shared__ u16 v_lds[64][64];
  __shared__ u16 p_lds[4][16][64];
  __shared__ float rk_lds[64][9];
  __shared__ float erv_lds[9][64];
  __shared__ float pband[64][9];
  const int tid = threadIdx.x, lane = tid & 63, wid = tid >> 6;
  const int l15 = lane & 15, l4 = lane >> 4;
  const int t0 = blockIdx.x * 64, bh = blockIdx.y;
  const int qrow = wid * 16 + l4 * 4;  // + j = this lane's q rows (block-local)

  const u16* qb = qbf + ((size_t)bh * NT + t0) * 64;
#pragma unroll
  for (int c = 0; c < 2; ++c) {
    int cc = wid * 2 + c;
    gld16(qb + cc * 512 + lane * 8, ((u16*)q_lds) + cc * 512);
  }
  {
    const float* rsrc = rkw + ((size_t)bh * NT + t0) * 9;
    for (int i = tid; i < 576; i += 256) {
      ((float*)rk_lds)[i] = rsrc[i];
      ((float*)erv_lds)[i] = erv[i];
      ((float*)pband)[i] = 0.f;
    }
  }
  __syncthreads();
  short8 qa[2];
  {
    int qr = wid * 16 + l15;
#pragma unroll
    for (int ks = 0; ks < 2; ++ks) {
      int off = (2 * (ks * 32 + l4 * 8)) ^ ((qr & 7) << 4);
      qa[ks] = *(const short8*)((const char*)&q_lds[qr][0] + off);
    }
  }
  f32x4 out[4] = {};
  float dsum[4] = {0.f, 0.f, 0.f, 0.f};
  const u16* kbase = kbf + (size_t)bh * NT * 64;
  const u16* vbase = vbf + (size_t)bh * 64 * NT;

  for (int s0 = 0; s0 < NT; s0 += 64) {
    __syncthreads();
#pragma unroll
    for (int c = 0; c < 2; ++c) {
      int cc = wid * 2 + c;
      gld16(kbase + (size_t)s0 * 64 + cc * 512 + lane * 8, ((u16*)k_lds) + cc * 512);
      int d = cc * 8 + (lane >> 3);
      gld16(vbase + (size_t)d * NT + s0 + (lane & 7) * 8, &v_lds[cc * 8][0]);
    }
    __syncthreads();
    f32x4 sf[4];
#pragma unroll
    for (int n = 0; n < 4; ++n) {
      int kr = n * 16 + l15;
      f32x4 a = {0.f, 0.f, 0.f, 0.f};
#pragma unroll
      for (int ks = 0; ks < 2; ++ks) {
        int off = (2 * (ks * 32 + l4 * 8)) ^ ((kr & 7) << 4);
        short8 kb = *(const short8*)((const char*)&k_lds[kr][0] + off);
        a = mfma16(qa[ks], kb, a);
      }
      sf[n] = a;
    }
    const unsigned du = (unsigned)(s0 - t0 + 64);
    if (du <= 128u) {  // s-chunk overlaps the |s-t|<=4 band
#pragma unroll
      for (int n = 0; n < 4; ++n)
#pragma unroll
        for (int j = 0; j < 4; ++j) {
          int dt = (s0 + n * 16 + l15) - (t0 + qrow + j);
          if (dt >= -4 && dt <= 4) sf[n][j] += rk_lds[qrow + j][dt + 4];
        }
    }
#pragma unroll
    for (int n = 0; n < 4; ++n)
#pragma unroll
      for (int j = 0; j < 4; ++j) {
        float p = __expf(sf[n][j]);
        sf[n][j] = p;
        dsum[j] += p;
      }
    if (du <= 128u) {  // record band p~ for the rel-v term
#pragma unroll
      for (int n = 0; n < 4; ++n)
#pragma unroll
        for (int j = 0; j < 4; ++j) {
          int dt = (s0 + n * 16 + l15) - (t0 + qrow + j);
          if (dt >= -4 && dt <= 4) pband[qrow + j][dt + 4] = sf[n][j];
        }
    }
    // P (C-layout) -> per-wave LDS -> A-layout fragments
#pragma unroll
    for (int n = 0; n < 4; ++n)
#pragma unroll
      for (int j = 0; j < 4; ++j) {
        int row = l4 * 4 + j;
        int off = (2 * (n * 16 + l15)) ^ ((row & 7) << 4);
        *(u16*)((char*)&p_lds[wid][row][0] + off) = f2bf(sf[n][j]);
      }
    short8 pa[2];
#pragma unroll
    for (int ks = 0; ks < 2; ++ks) {
      int off = (2 * (ks * 32 + l4 * 8)) ^ ((l15 & 7) << 4);
      pa[ks] = *(const short8*)((const char*)&p_lds[wid][l15][0] + off);
    }
#pragma unroll
    for (int n = 0; n < 4; ++n)
#pragma unroll
      for (int ks = 0; ks < 2; ++ks) {
        int vr = n * 16 + l15;
        int off = (2 * (ks * 32 + l4 * 8)) ^ ((vr & 7) << 4);
        short8 vb = *(const short8*)((const char*)&v_lds[vr][0] + off);
        out[n] = mfma16(pa[ks], vb, out[n]);
      }
  }
#pragma unroll
  for (int m = 1; m < 16; m <<= 1)
#pragma unroll
    for (int j = 0; j < 4; ++j) dsum[j] += __shfl_xor(dsum[j], m, 64);
  float rd[4];
#pragma unroll
  for (int j = 0; j < 4; ++j) rd[j] = 1.f / dsum[j];
  const int b = bh / NH, h = bh % NH;
#pragma unroll
  for (int n = 0; n < 4; ++n) {
    int d = n * 16 + l15;
#pragma unroll
    for (int j = 0; j < 4; ++j) {
      int q = qrow + j;
      float v = out[n][j];
#pragma unroll
      for (int m2 = 0; m2 < 9; ++m2) v += pband[q][m2] * erv_lds[m2][d];
      v *= rd[j];
      int tg = t0 + q;
      size_t base = ((size_t)(b * NT + tg) * NC + h * 64) * 2;
      int off = (2 * d) ^ ((tg & 7) << 4);
      u16 hi = f2bf(v);
      *(u16*)((char*)ohi + base + off) = hi;
      *(u16*)((char*)olo + base + off) = f2bf(v - bf2f(hi));
    }
  }
}

extern "C" void kernel_launch(void* const* d_in, const int* in_sizes, int n_in, void* d_out, int out_size,
                              void* d_ws, size_t ws_size, hipStream_t stream) {
  const float* x = (const float*)d_in[0];
  const float* c = (const float*)d_in[1];
  const float* wq = (const float*)d_in[2];
  const float* bq = (const float*)d_in[3];
  const float* wk = (const float*)d_in[4];
  const float* bk = (const float*)d_in[5];
  const float* wv = (const float*)d_in[6];
  const float* bv = (const float*)d_in[7];
  const float* wo = (const float*)d_in[8];
  const float* bo = (const float*)d_in[9];
  const float* erk = (const float*)d_in[10];
  const float* erv = (const float*)d_in[11];

  char* ws = (char*)d_ws;
  size_t off = 0;
  auto alloc = [&](size_t bytes) {
    void* p = ws + off;
    off += (bytes + 255) & ~(size_t)255;
    return p;
  };
  const size_t SZ_XT = (size_t)NB * NT * NC * 2;   // 12.6 MB
  const size_t SZ_W = (size_t)NC * NC * 2;         // 1.18 MB
  const size_t SZ_QKV = (size_t)NBH * NT * ND * 2; // 12.6 MB
  u16* xT_hi = (u16*)alloc(SZ_XT);
  u16* xT_lo = (u16*)alloc(SZ_XT);
  u16* cT_hi = (u16*)alloc(SZ_XT);
  u16* cT_lo = (u16*)alloc(SZ_XT);
  u16* wq_hi = (u16*)alloc(SZ_W);
  u16* wq_lo = (u16*)alloc(SZ_W);
  u16* wk_hi = (u16*)alloc(SZ_W);
  u16* wk_lo = (u16*)alloc(SZ_W);
  u16* wv_hi = (u16*)alloc(SZ_W);
  u16* wv_lo = (u16*)alloc(SZ_W);
  u16* wo_hi = (u16*)alloc(SZ_W);
  u16* wo_lo = (u16*)alloc(SZ_W);
  u16* qbf = (u16*)alloc(SZ_QKV);
  u16* kbf = (u16*)alloc(SZ_QKV);
  u16* vbf = (u16*)alloc(SZ_QKV);
  float* rkw = (float*)alloc((size_t)NBH * NT * 9 * 4);
  u16* oT_hi = (u16*)alloc(SZ_XT);
  u16* oT_lo = (u16*)alloc(SZ_XT);

  k_split_T<<<dim3(16, 12, 8), 256, 0, stream>>>(x, xT_hi, xT_lo);
  k_split_T<<<dim3(16, 12, 8), 256, 0, stream>>>(c, cT_hi, cT_lo);
  k_split_W<<<dim3(12, 12), 256, 0, stream>>>(wq, wq_hi, wq_lo);
  k_split_W<<<dim3(12, 12), 256, 0, stream>>>(wk, wk_hi, wk_lo);
  k_split_W<<<dim3(12, 12), 256, 0, stream>>>(wv, wv_hi, wv_lo);
  k_split_W<<<dim3(12, 12), 256, 0, stream>>>(wo, wo_hi, wo_lo);
  k_proj<0><<<dim3(8, 6, 8), 256, 0, stream>>>(xT_hi, xT_lo, wq_hi, wq_lo, bq, qbf);
  k_proj<1><<<dim3(8, 6, 8), 256, 0, stream>>>(cT_hi, cT_lo, wk_hi, wk_lo, bk, kbf);
  k_proj<2><<<dim3(8, 6, 8), 256, 0, stream>>>(cT_hi, cT_lo, wv_hi, wv_lo, bv, vbf);
  k_rk<<<dim3(NBH * NT / 256), 256, 0, stream>>>(qbf, erk, rkw);
  k_attn<<<dim3(16, NBH), 256, 0, stream>>>(qbf, kbf, vbf, rkw, erv, oT_hi, oT_lo);
  k_proj<3><<<dim3(8, 6, 8), 256, 0, stream>>>(oT_hi, oT_lo, wo_hi, wo_lo, bo, d_out);
}